// Round 3
// baseline (262.096 us; speedup 1.0000x reference)
//
#include <hip/hip_runtime.h>
#include <hip/hip_fp16.h>

typedef unsigned short u16;
typedef unsigned int u32;
typedef __attribute__((ext_vector_type(8))) short short8;
typedef __attribute__((ext_vector_type(4))) float f32x4;

#define MFMA16(a, b, c) __builtin_amdgcn_mfma_f32_16x16x32_bf16((a), (b), (c), 0, 0, 0)

#define ESTRIDE 2304  // per-graph CSR slot count: 2048 avg + 5.7 sigma

__device__ __forceinline__ float b2f(u16 u) {
  union { float f; unsigned int i; } v;
  v.i = ((unsigned int)u) << 16;
  return v.f;
}
__device__ __forceinline__ u16 f2b(float f) {
  union { float f; unsigned int i; } v;
  v.f = f;
  unsigned int x = v.i;
  return (u16)((x + 0x7FFFu + ((x >> 16) & 1u)) >> 16);
}
__device__ __forceinline__ u16 f2h_bits(float f) {
  __half h = __float2half(f);
  u16 b;
  __builtin_memcpy(&b, &h, 2);
  return b;
}
__device__ __forceinline__ float h2f_bits(u16 b) {
  __half h;
  __builtin_memcpy(&h, &b, 2);
  return __half2float(h);
}

__device__ __forceinline__ void gload_lds16(const u16* g, u16* l) {
  __builtin_amdgcn_global_load_lds(
      (const __attribute__((address_space(1))) void*)g,
      (__attribute__((address_space(3))) void*)l, 16, 0, 0);
}

// ---------------------------------------------------------------------------
// Merged: x (fp32)->bf16 (blocks 0..4095) + weight transpose (blocks 4096..4223)
// ---------------------------------------------------------------------------
__global__ __launch_bounds__(256) void cvt_wtrans_kernel(
    const float* __restrict__ x, u16* __restrict__ xb,
    const float* __restrict__ W0, const float* __restrict__ W1,
    const float* __restrict__ W2, const float* __restrict__ W3,
    u16* __restrict__ T0, u16* __restrict__ T1,
    u16* __restrict__ T2, u16* __restrict__ T3) {
  int bx = blockIdx.x;
  if (bx < 4096) {
    size_t i = ((size_t)bx * 256 + threadIdx.x) * 8;
    const float4* p = (const float4*)(x + i);
    float4 v0 = p[0], v1 = p[1];
    float vf[8] = {v0.x, v0.y, v0.z, v0.w, v1.x, v1.y, v1.z, v1.w};
    short8 s;
#pragma unroll
    for (int j = 0; j < 8; ++j) s[j] = (short)f2b(vf[j]);
    *(short8*)(xb + i) = s;
  } else {
    int r = bx - 4096;
    const float* W; u16* T;
    switch (r >> 5) {
      case 0: W = W0; T = T0; break;
      case 1: W = W1; T = T1; break;
      case 2: W = W2; T = T2; break;
      default: W = W3; T = T3; break;
    }
    int n = threadIdx.x;
    int k0 = (r & 31) * 8;
    short8 s;
#pragma unroll
    for (int j = 0; j < 8; ++j) s[j] = (short)f2b(W[(size_t)(k0 + j) * 256 + n]);
    *(short8*)(T + (size_t)n * 256 + k0) = s;
  }
}

// ---------------------------------------------------------------------------
// Edge CSR build at fixed stride: LDS histogram -> one padded global atomic
// per non-empty bin -> scatter via LDS cursors. Totals fp16 AoS (16B store).
// ---------------------------------------------------------------------------
__global__ __launch_bounds__(256) void edge_build_kernel(
    const int* __restrict__ ei, const float* __restrict__ ea,
    const int* __restrict__ egt, const float* __restrict__ gate_table,
    const float* __restrict__ We, const float* __restrict__ be,
    u32* __restrict__ gfill, u16* __restrict__ etot16,
    u32* __restrict__ epos, int E) {
  __shared__ u32 hist[256];
  __shared__ u32 cursor[256];
  const int tid = threadIdx.x;
  hist[tid] = 0;
  __syncthreads();
  const int base_e = blockIdx.x * 2048;
  int gcache[8];
#pragma unroll
  for (int i = 0; i < 8; ++i) {
    int e = base_e + i * 256 + tid;
    int g = (e < E) ? (ei[e] >> 7) : -1;
    gcache[i] = g;
    if (g >= 0) atomicAdd(&hist[(u32)g], 1u);
  }
  __syncthreads();
  {
    u32 c = hist[tid];
    u32 r = c ? atomicAdd(&gfill[tid * 16], c) : 0u;
    cursor[tid] = (u32)tid * ESTRIDE + r;
  }
  __syncthreads();
#pragma unroll
  for (int i = 0; i < 8; ++i) {
    int g = gcache[i];
    if (g < 0) continue;
    int e = base_e + i * 256 + tid;
    int src = ei[e], dst = ei[E + e];
    int sl = src & 127, dl = dst & 127;
    int gt = egt[e];
    const float4* eap = (const float4*)(ea + (size_t)e * 8);
    float4 e0 = eap[0], e1 = eap[1];
    float eaf[8] = {e0.x, e0.y, e0.z, e0.w, e1.x, e1.y, e1.z, e1.w};
    short8 sv;
#pragma unroll
    for (int h = 0; h < 8; ++h) {
      float s = gate_table[gt * 8 + h] + be[h];
#pragma unroll
      for (int f = 0; f < 8; ++f) s += eaf[f] * We[f * 8 + h];
      sv[h] = (short)f2h_bits(s);
    }
    u32 pos = atomicAdd(&cursor[(u32)g], 1u);
    epos[pos] = (u32)sl | ((u32)dl << 16);
    *(short8*)(etot16 + (size_t)pos * 8) = sv;
  }
}

// ---------------------------------------------------------------------------
// fp16 AoS [slot][h] -> SoA [h][slot], zero-padding slots beyond fill count.
// grid (ESTRIDE/256, 256 graphs)
// ---------------------------------------------------------------------------
__global__ __launch_bounds__(256) void etrans_pad_kernel(
    const u16* __restrict__ aos, const u32* __restrict__ gfill,
    u16* __restrict__ soa, u32* __restrict__ epos) {
  int g = blockIdx.y;
  int p = blockIdx.x * 256 + threadIdx.x;
  u32 cnt = gfill[g * 16];
  size_t idx = (size_t)g * ESTRIDE + p;
  const size_t plane = (size_t)256 * ESTRIDE;
  if ((u32)p < cnt) {
    short8 v = *(const short8*)(aos + idx * 8);
#pragma unroll
    for (int h = 0; h < 8; ++h) soa[plane * h + idx] = (u16)v[h];
  } else {
    epos[idx] = 0;  // self-loop pad
#pragma unroll
    for (int h = 0; h < 8; ++h) soa[plane * h + idx] = 0;
  }
}

// ---------------------------------------------------------------------------
// m97-style tiled GEMM: 128x128 tile, BK=64, global_load_lds staging into a
// single 32KB LDS buffer (2 barriers per K-step), XOR-16B swizzle applied on
// the pre-swizzled global source (gload_lds writes linearly) and on ds_read.
// Grid: (M/128, NMAT*2).  blockIdx.y -> (matrix, 128-col half).
// C_m = (A @ Wt_m^T + bias_m) * scale_m, Wt is [n][k] row-major (k contig).
// ---------------------------------------------------------------------------
template <int NMAT, typename COUT>
__global__ __launch_bounds__(256) void gemm_tiled_kernel(
    const u16* __restrict__ A,
    const u16* __restrict__ T0, const u16* __restrict__ T1,
    const u16* __restrict__ T2,
    const float* __restrict__ b0, const float* __restrict__ b1,
    const float* __restrict__ b2,
    float s0, float s1, float s2,
    COUT* __restrict__ C0, COUT* __restrict__ C1, COUT* __restrict__ C2) {
  __shared__ __align__(16) u16 lA[128 * 64];
  __shared__ __align__(16) u16 lB[128 * 64];

  const int tid = threadIdx.x;
  const int bm = blockIdx.x;
  const int bn = blockIdx.y;
  const int m  = (NMAT == 1) ? 0 : (bn >> 1);
  const int ch = (NMAT == 1) ? bn : (bn & 1);

  const u16* Ts[3] = {T0, T1, T2};
  const float* bs[3] = {b0, b1, b2};
  const float scs[3] = {s0, s1, s2};
  COUT* Cs[3] = {C0, C1, C2};

  const u16* Abase = A + (size_t)(bm * 128) * 256;
  const u16* Bbase = Ts[m] + (size_t)(ch * 128) * 256;

  int srow[4];
  int selem[4];  // swizzled element offset within the 64-wide k-slice
#pragma unroll
  for (int i = 0; i < 4; ++i) {
    int c = i * 256 + tid;
    int row = c >> 3;
    int q = (c & 7) * 16;           // byte within 128B row
    srow[i] = row;
    selem[i] = (q ^ ((row & 7) << 4)) >> 1;
  }

  const int wid = tid >> 6, lane = tid & 63;
  const int wm = wid >> 1, wn = wid & 1;
  const int quad = lane >> 4, l16 = lane & 15;
  const int swz = (l16 & 7) << 4;   // row&7 == l16&7 for all fragment rows

  f32x4 acc[4][4] = {};

#pragma unroll
  for (int kt = 0; kt < 4; ++kt) {
    const int k0 = kt * 64;
    __syncthreads();  // previous tile's ds_reads complete before overwrite
#pragma unroll
    for (int i = 0; i < 4; ++i) {
      gload_lds16(Abase + (size_t)srow[i] * 256 + k0 + selem[i],
                  lA + (size_t)(i * 256 + tid) * 8);
      gload_lds16(Bbase + (size_t)srow[i] * 256 + k0 + selem[i],
                  lB + (size_t)(i * 256 + tid) * 8);
    }
    __syncthreads();  // vmcnt(0) drain: tile visible

#pragma unroll
    for (int ks = 0; ks < 2; ++ks) {
      const int kb = (ks * 64 + quad * 16) ^ swz;  // byte within row
      short8 af[4], bf[4];
#pragma unroll
      for (int i = 0; i < 4; ++i) {
        int arow = wm * 64 + i * 16 + l16;
        af[i] = *(const short8*)((const char*)lA + arow * 128 + kb);
        int brow = wn * 64 + i * 16 + l16;
        bf[i] = *(const short8*)((const char*)lB + brow * 128 + kb);
      }
#pragma unroll
      for (int i = 0; i < 4; ++i)
#pragma unroll
        for (int j = 0; j < 4; ++j)
          acc[i][j] = MFMA16(af[i], bf[j], acc[i][j]);
    }
  }

  const float* bias = bs[m];
  const float sc = scs[m];
  COUT* C = Cs[m];
#pragma unroll
  for (int j = 0; j < 4; ++j) {
    int col = ch * 128 + wn * 64 + j * 16 + l16;
    float bv = bias[col];
#pragma unroll
    for (int i = 0; i < 4; ++i) {
      int row0 = bm * 128 + wm * 64 + i * 16 + quad * 4;
#pragma unroll
      for (int r = 0; r < 4; ++r) {
        float o = (acc[i][j][r] + bv) * sc;
        if constexpr (sizeof(COUT) == 4)
          C[(size_t)(row0 + r) * 256 + col] = o;
        else
          C[(size_t)(row0 + r) * 256 + col] = f2b(o);
      }
    }
  }
}

// ---------------------------------------------------------------------------
// Fused attention, one block per (q-quarter, head, graph): 32x128 S tile,
// 256 threads (4 waves).  18.0 KB LDS -> 8 blocks/CU = 32 waves/CU (full
// wave-slot occupancy); the 4-phase barrier chain of each block is overlapped
// by 7 other resident blocks.  Edge scan is 4x redundant (25% atomic
// liveness) but slices are L2/L3-resident.  Linear S (LS=132): softmax
// float4 reads and QK writes are 2-way conflicted == free (m136).
// ---------------------------------------------------------------------------
__global__ __launch_bounds__(256, 8) void attn_kernel(
    const u16* __restrict__ Q, const u16* __restrict__ K,
    const u16* __restrict__ V, const u32* __restrict__ epos,
    const u16* __restrict__ etot16, u16* __restrict__ O) {
  constexpr int LV = 144, LP = 136, LS = 132;
  constexpr int NE = ESTRIDE / 256;  // 9
  __shared__ __align__(16) char smem[18048];
  float* S   = (float*)smem;                    // 32*132*4 = 16896 B
  u16*   Pb  = (u16*)smem;                      // 32*136*2 =  8704 B (alias S)
  u16*   Vt  = (u16*)(smem + 8704);             // 32*144*2 =  9216 B (alias S)
  float* inv = (float*)(smem + 17920);          //   128 B (beyond S)

  const int tid = threadIdx.x;
  const int qq = blockIdx.x, h = blockIdx.y, b = blockIdx.z;
  const int q0 = qq * 32;
  const int wid = tid >> 6, lane = tid & 63;
  const int quad = lane >> 4, l16 = lane & 15;

  // Prefetch this block's edge slice into registers (fixed trip count)
  u32 pd[NE]; u16 tb[NE];
  {
    const u32* ep = epos + (size_t)b * ESTRIDE + tid;
    const u16* ets = etot16 + (size_t)h * (256 * ESTRIDE) + (size_t)b * ESTRIDE + tid;
#pragma unroll
    for (int i = 0; i < NE; ++i) pd[i] = ep[i * 256];
#pragma unroll
    for (int i = 0; i < NE; ++i) tb[i] = ets[i * 256];
  }

  // Load full V tile (128x32) into registers; scattered to LDS after softmax
  const int vr = tid >> 1, vs = (tid & 1) * 16;
  short8 vreg0, vreg1;
  {
    const u16* p = V + (size_t)(b * 128 + vr) * 256 + h * 32 + vs;
    vreg0 = *(const short8*)p;
    vreg1 = *(const short8*)(p + 8);
  }

  // S = Q @ K^T for rows q0..q0+31 (scale pre-folded into Q).
  // wave wid: row stripe (wid&1)*16, col half (wid>>1)*64.
  {
    const int sr = (wid & 1) * 16, kh = (wid >> 1) * 64;
    short8 aq = *(const short8*)(
        Q + (size_t)(b * 128 + q0 + sr + l16) * 256 + h * 32 + quad * 8);
#pragma unroll
    for (int j = 0; j < 4; ++j) {
      short8 bk = *(const short8*)(
          K + (size_t)(b * 128 + kh + j * 16 + l16) * 256 + h * 32 + quad * 8);
      f32x4 z = {0.f, 0.f, 0.f, 0.f};
      f32x4 sv = MFMA16(aq, bk, z);
#pragma unroll
      for (int r = 0; r < 4; ++r)
        S[(sr + quad * 4 + r) * LS + kh + j * 16 + l16] = sv[r];
    }
  }
  __syncthreads();

  // Edge bias via LDS atomics; only rows within this q-quarter are live
#pragma unroll
  for (int i = 0; i < NE; ++i) {
    int sl = pd[i] & 0xffff, dl = pd[i] >> 16;
    float t = h2f_bits(tb[i]);
    int sr = sl - q0, dr = dl - q0;
    if ((unsigned)sr < 32u) atomicAdd(&S[sr * LS + dl], t);
    if (sl != dl && (unsigned)dr < 32u) atomicAdd(&S[dr * LS + sl], t);
  }
  __syncthreads();

  // Softmax: 8 threads/row, 16 cols each; float4 S reads (2-way, free)
  {
    int row = tid >> 3, t8 = tid & 7, c0 = t8 * 16;
    const float* srow = &S[row * LS + c0];
    float sv[16];
#pragma unroll
    for (int k = 0; k < 4; ++k) {
      float4 v = *(const float4*)(srow + k * 4);
      sv[k * 4 + 0] = v.x; sv[k * 4 + 1] = v.y;
      sv[k * 4 + 2] = v.z; sv[k * 4 + 3] = v.w;
    }
    float m = -1e30f;
#pragma unroll
    for (int c = 0; c < 16; ++c) m = fmaxf(m, sv[c]);
    m = fmaxf(m, __shfl_xor(m, 1, 64));
    m = fmaxf(m, __shfl_xor(m, 2, 64));
    m = fmaxf(m, __shfl_xor(m, 4, 64));
    float sum = 0.f;
    short8 prow[2];
#pragma unroll
    for (int c = 0; c < 16; ++c) {
      float p = __expf(sv[c] - m);
      sum += p;
      prow[c >> 3][c & 7] = (short)f2b(p);
    }
    sum += __shfl_xor(sum, 1, 64);
    sum += __shfl_xor(sum, 2, 64);
    sum += __shfl_xor(sum, 4, 64);
    __syncthreads();  // all S reads done; Pb/Vt may overwrite S region
#pragma unroll
    for (int k = 0; k < 2; ++k)
      *(short8*)&Pb[row * LP + c0 + k * 8] = prow[k];
#pragma unroll
    for (int j = 0; j < 8; ++j) {
      Vt[(vs + j) * LV + vr] = (u16)vreg0[j];
      Vt[(vs + 8 + j) * LV + vr] = (u16)vreg1[j];
    }
    if (t8 == 0) inv[row] = 1.f / sum;
  }
  __syncthreads();

  // O = (P @ V) * inv ; wave wid: row stripe (wid&1)*16, dh half (wid>>1)*16
  {
    const int s = (wid & 1) * 16, c = (wid >> 1) * 16;
    f32x4 oacc = {};
#pragma unroll
    for (int ks = 0; ks < 4; ++ks) {
      short8 ap = *(short8*)&Pb[(s + l16) * LP + ks * 32 + quad * 8];
      short8 bv = *(short8*)&Vt[(c + l16) * LV + ks * 32 + quad * 8];
      oacc = MFMA16(ap, bv, oacc);
    }
#pragma unroll
    for (int r = 0; r < 4; ++r) {
      int qr = s + quad * 4 + r;
      float iv = inv[qr];
      O[(size_t)(b * 128 + q0 + qr) * 256 + h * 32 + c + l16] =
          f2b(oacc[r] * iv);
    }
  }
}

// ---------------------------------------------------------------------------

extern "C" void kernel_launch(void* const* d_in, const int* in_sizes, int n_in,
                              void* d_out, int out_size, void* d_ws, size_t ws_size,
                              hipStream_t stream) {
  const float* x    = (const float*)d_in[0];
  const float* ea   = (const float*)d_in[1];
  const float* Wq   = (const float*)d_in[2];
  const float* bq   = (const float*)d_in[3];
  const float* Wk   = (const float*)d_in[4];
  const float* bk   = (const float*)d_in[5];
  const float* Wv   = (const float*)d_in[6];
  const float* bv   = (const float*)d_in[7];
  const float* Wo   = (const float*)d_in[8];
  const float* bo   = (const float*)d_in[9];
  const float* gate = (const float*)d_in[10];
  const float* We   = (const float*)d_in[11];
  const float* be   = (const float*)d_in[12];
  const int*   ei   = (const int*)d_in[13];
  const int*   egt  = (const int*)d_in[14];
  const int    E    = in_sizes[14];

  const size_t matBytes = (size_t)32768 * 256 * 2;   // 16.78 MB per bf16 matrix
  const size_t slots = (size_t)256 * ESTRIDE;        // 589824

  char* ws = (char*)d_ws;
  u16* Qm = (u16*)ws;
  u16* Km = (u16*)(ws + matBytes);
  u16* Vm = (u16*)(ws + 2 * matBytes);
  u16* Om = (u16*)(ws + 3 * matBytes);
  u16* xb = Om;  // xb aliases Om: xb dead before attn writes Om
  u16*   etA  = (u16*)(ws + 4 * matBytes);                 // slots*8 fp16 AoS
  u16*   etS  = etA + slots * 8;                           // slots*8 fp16 SoA
  u32*   epos = (u32*)(etS + slots * 8);                   // slots u32
  u32*   gfill = (u32*)((char*)epos + slots * 4);          // 256 ctrs, 64B apart
  u16*   Wtq = (u16*)((char*)gfill + 4096 * 4);            // 4 x 64K bf16
  u16*   Wtk = Wtq + 65536;
  u16*   Wtv = Wtk + 65536;
  u16*   Wto = Wtv + 65536;

  hipMemsetAsync(gfill, 0, 4096 * sizeof(u32), stream);

  edge_build_kernel<<<dim3((E + 2047) / 2048), dim3(256), 0, stream>>>(
      ei, ea, egt, gate, We, be, gfill, etA, epos, E);
  etrans_pad_kernel<<<dim3(ESTRIDE / 256, 256), dim3(256), 0, stream>>>(
      etA, gfill, etS, epos);

  cvt_wtrans_kernel<<<dim3(4224), dim3(256), 0, stream>>>(
      x, xb, Wq, Wk, Wv, Wo, Wtq, Wtk, Wtv, Wto);

  const float qscale = 0.17677669529663687f;
  gemm_tiled_kernel<3, u16><<<dim3(256, 6), dim3(256), 0, stream>>>(
      xb, Wtq, Wtk, Wtv, bq, bk, bv, qscale, 1.f, 1.f, Qm, Km, Vm);

  attn_kernel<<<dim3(4, 8, 256), dim3(256), 0, stream>>>(
      Qm, Km, Vm, epos, etS, Om);

  gemm_tiled_kernel<1, float><<<dim3(256, 2), dim3(256), 0, stream>>>(
      Om, Wto, nullptr, nullptr, bo, nullptr, nullptr, 1.f, 1.f, 1.f,
      (float*)d_out, nullptr, nullptr);
}

// Round 5
// 218.565 us; speedup vs baseline: 1.1992x; 1.1992x over previous
//
#include <hip/hip_runtime.h>
#include <hip/hip_fp16.h>

typedef unsigned short u16;
typedef unsigned int u32;
typedef __attribute__((ext_vector_type(8))) short short8;
typedef __attribute__((ext_vector_type(4))) float f32x4;

#define MFMA16(a, b, c) __builtin_amdgcn_mfma_f32_16x16x32_bf16((a), (b), (c), 0, 0, 0)

#define ESTRIDE 2304  // per-graph CSR slot count: 2048 avg + 5.7 sigma

// S fixed-point scale: integer LDS atomicAdd (ds_add_u32, always native --
// no CAS expansion like float atomicAdd) on S stored as int(s * 2^24).
#define FIXSCALE 16777216.0f
#define FIXINV   5.9604644775390625e-8f

__device__ __forceinline__ float b2f(u16 u) {
  union { float f; unsigned int i; } v;
  v.i = ((unsigned int)u) << 16;
  return v.f;
}
__device__ __forceinline__ u16 f2b(float f) {
  union { float f; unsigned int i; } v;
  v.f = f;
  unsigned int x = v.i;
  return (u16)((x + 0x7FFFu + ((x >> 16) & 1u)) >> 16);
}
__device__ __forceinline__ u16 f2h_bits(float f) {
  __half h = __float2half(f);
  u16 b;
  __builtin_memcpy(&b, &h, 2);
  return b;
}
__device__ __forceinline__ float h2f_bits(u16 b) {
  __half h;
  __builtin_memcpy(&h, &b, 2);
  return __half2float(h);
}

__device__ __forceinline__ void gload_lds16(const u16* g, u16* l) {
  __builtin_amdgcn_global_load_lds(
      (const __attribute__((address_space(1))) void*)g,
      (__attribute__((address_space(3))) void*)l, 16, 0, 0);
}

// ---------------------------------------------------------------------------
// Merged: x (fp32)->bf16 (blocks 0..4095) + weight transpose (blocks 4096..4223)
// ---------------------------------------------------------------------------
__global__ __launch_bounds__(256) void cvt_wtrans_kernel(
    const float* __restrict__ x, u16* __restrict__ xb,
    const float* __restrict__ W0, const float* __restrict__ W1,
    const float* __restrict__ W2, const float* __restrict__ W3,
    u16* __restrict__ T0, u16* __restrict__ T1,
    u16* __restrict__ T2, u16* __restrict__ T3) {
  int bx = blockIdx.x;
  if (bx < 4096) {
    size_t i = ((size_t)bx * 256 + threadIdx.x) * 8;
    const float4* p = (const float4*)(x + i);
    float4 v0 = p[0], v1 = p[1];
    float vf[8] = {v0.x, v0.y, v0.z, v0.w, v1.x, v1.y, v1.z, v1.w};
    short8 s;
#pragma unroll
    for (int j = 0; j < 8; ++j) s[j] = (short)f2b(vf[j]);
    *(short8*)(xb + i) = s;
  } else {
    int r = bx - 4096;
    const float* W; u16* T;
    switch (r >> 5) {
      case 0: W = W0; T = T0; break;
      case 1: W = W1; T = T1; break;
      case 2: W = W2; T = T2; break;
      default: W = W3; T = T3; break;
    }
    int n = threadIdx.x;
    int k0 = (r & 31) * 8;
    short8 s;
#pragma unroll
    for (int j = 0; j < 8; ++j) s[j] = (short)f2b(W[(size_t)(k0 + j) * 256 + n]);
    *(short8*)(T + (size_t)n * 256 + k0) = s;
  }
}

// ---------------------------------------------------------------------------
// Edge CSR build at fixed stride: LDS histogram -> one padded global atomic
// per non-empty bin -> scatter via LDS cursors. Totals fp16 AoS (16B store).
// ---------------------------------------------------------------------------
__global__ __launch_bounds__(256) void edge_build_kernel(
    const int* __restrict__ ei, const float* __restrict__ ea,
    const int* __restrict__ egt, const float* __restrict__ gate_table,
    const float* __restrict__ We, const float* __restrict__ be,
    u32* __restrict__ gfill, u16* __restrict__ etot16,
    u32* __restrict__ epos, int E) {
  __shared__ u32 hist[256];
  __shared__ u32 cursor[256];
  const int tid = threadIdx.x;
  hist[tid] = 0;
  __syncthreads();
  const int base_e = blockIdx.x * 2048;
  int gcache[8];
#pragma unroll
  for (int i = 0; i < 8; ++i) {
    int e = base_e + i * 256 + tid;
    int g = (e < E) ? (ei[e] >> 7) : -1;
    gcache[i] = g;
    if (g >= 0) atomicAdd(&hist[(u32)g], 1u);
  }
  __syncthreads();
  {
    u32 c = hist[tid];
    u32 r = c ? atomicAdd(&gfill[tid * 16], c) : 0u;
    cursor[tid] = (u32)tid * ESTRIDE + r;
  }
  __syncthreads();
#pragma unroll
  for (int i = 0; i < 8; ++i) {
    int g = gcache[i];
    if (g < 0) continue;
    int e = base_e + i * 256 + tid;
    int src = ei[e], dst = ei[E + e];
    int sl = src & 127, dl = dst & 127;
    int gt = egt[e];
    const float4* eap = (const float4*)(ea + (size_t)e * 8);
    float4 e0 = eap[0], e1 = eap[1];
    float eaf[8] = {e0.x, e0.y, e0.z, e0.w, e1.x, e1.y, e1.z, e1.w};
    short8 sv;
#pragma unroll
    for (int h = 0; h < 8; ++h) {
      float s = gate_table[gt * 8 + h] + be[h];
#pragma unroll
      for (int f = 0; f < 8; ++f) s += eaf[f] * We[f * 8 + h];
      sv[h] = (short)f2h_bits(s);
    }
    u32 pos = atomicAdd(&cursor[(u32)g], 1u);
    epos[pos] = (u32)sl | ((u32)dl << 16);
    *(short8*)(etot16 + (size_t)pos * 8) = sv;
  }
}

// ---------------------------------------------------------------------------
// fp16 AoS [slot][h] -> SoA [h][slot], zero-padding slots beyond fill count.
// grid (ESTRIDE/256, 256 graphs)
// ---------------------------------------------------------------------------
__global__ __launch_bounds__(256) void etrans_pad_kernel(
    const u16* __restrict__ aos, const u32* __restrict__ gfill,
    u16* __restrict__ soa, u32* __restrict__ epos) {
  int g = blockIdx.y;
  int p = blockIdx.x * 256 + threadIdx.x;
  u32 cnt = gfill[g * 16];
  size_t idx = (size_t)g * ESTRIDE + p;
  const size_t plane = (size_t)256 * ESTRIDE;
  if ((u32)p < cnt) {
    short8 v = *(const short8*)(aos + idx * 8);
#pragma unroll
    for (int h = 0; h < 8; ++h) soa[plane * h + idx] = (u16)v[h];
  } else {
    epos[idx] = 0;  // self-loop pad
#pragma unroll
    for (int h = 0; h < 8; ++h) soa[plane * h + idx] = 0;
  }
}

// ---------------------------------------------------------------------------
// m97-style tiled GEMM: 128x128 tile, BK=64, global_load_lds staging into a
// single 32KB LDS buffer (2 barriers per K-step), XOR-16B swizzle applied on
// the pre-swizzled global source (gload_lds writes linearly) and on ds_read.
// Grid: (M/128, NMAT*2).  blockIdx.y -> (matrix, 128-col half).
// C_m = (A @ Wt_m^T + bias_m) * scale_m, Wt is [n][k] row-major (k contig).
// ---------------------------------------------------------------------------
template <int NMAT, typename COUT>
__global__ __launch_bounds__(256) void gemm_tiled_kernel(
    const u16* __restrict__ A,
    const u16* __restrict__ T0, const u16* __restrict__ T1,
    const u16* __restrict__ T2,
    const float* __restrict__ b0, const float* __restrict__ b1,
    const float* __restrict__ b2,
    float s0, float s1, float s2,
    COUT* __restrict__ C0, COUT* __restrict__ C1, COUT* __restrict__ C2) {
  __shared__ __align__(16) u16 lA[128 * 64];
  __shared__ __align__(16) u16 lB[128 * 64];

  const int tid = threadIdx.x;
  const int bm = blockIdx.x;
  const int bn = blockIdx.y;
  const int m  = (NMAT == 1) ? 0 : (bn >> 1);
  const int ch = (NMAT == 1) ? bn : (bn & 1);

  const u16* Ts[3] = {T0, T1, T2};
  const float* bs[3] = {b0, b1, b2};
  const float scs[3] = {s0, s1, s2};
  COUT* Cs[3] = {C0, C1, C2};

  const u16* Abase = A + (size_t)(bm * 128) * 256;
  const u16* Bbase = Ts[m] + (size_t)(ch * 128) * 256;

  int srow[4];
  int selem[4];  // swizzled element offset within the 64-wide k-slice
#pragma unroll
  for (int i = 0; i < 4; ++i) {
    int c = i * 256 + tid;
    int row = c >> 3;
    int q = (c & 7) * 16;           // byte within 128B row
    srow[i] = row;
    selem[i] = (q ^ ((row & 7) << 4)) >> 1;
  }

  const int wid = tid >> 6, lane = tid & 63;
  const int wm = wid >> 1, wn = wid & 1;
  const int quad = lane >> 4, l16 = lane & 15;
  const int swz = (l16 & 7) << 4;   // row&7 == l16&7 for all fragment rows

  f32x4 acc[4][4] = {};

#pragma unroll
  for (int kt = 0; kt < 4; ++kt) {
    const int k0 = kt * 64;
    __syncthreads();  // previous tile's ds_reads complete before overwrite
#pragma unroll
    for (int i = 0; i < 4; ++i) {
      gload_lds16(Abase + (size_t)srow[i] * 256 + k0 + selem[i],
                  lA + (size_t)(i * 256 + tid) * 8);
      gload_lds16(Bbase + (size_t)srow[i] * 256 + k0 + selem[i],
                  lB + (size_t)(i * 256 + tid) * 8);
    }
    __syncthreads();  // vmcnt(0) drain: tile visible

#pragma unroll
    for (int ks = 0; ks < 2; ++ks) {
      const int kb = (ks * 64 + quad * 16) ^ swz;  // byte within row
      short8 af[4], bf[4];
#pragma unroll
      for (int i = 0; i < 4; ++i) {
        int arow = wm * 64 + i * 16 + l16;
        af[i] = *(const short8*)((const char*)lA + arow * 128 + kb);
        int brow = wn * 64 + i * 16 + l16;
        bf[i] = *(const short8*)((const char*)lB + brow * 128 + kb);
      }
#pragma unroll
      for (int i = 0; i < 4; ++i)
#pragma unroll
        for (int j = 0; j < 4; ++j)
          acc[i][j] = MFMA16(af[i], bf[j], acc[i][j]);
    }
  }

  const float* bias = bs[m];
  const float sc = scs[m];
  COUT* C = Cs[m];
#pragma unroll
  for (int j = 0; j < 4; ++j) {
    int col = ch * 128 + wn * 64 + j * 16 + l16;
    float bv = bias[col];
#pragma unroll
    for (int i = 0; i < 4; ++i) {
      int row0 = bm * 128 + wm * 64 + i * 16 + quad * 4;
#pragma unroll
      for (int r = 0; r < 4; ++r) {
        float o = (acc[i][j][r] + bv) * sc;
        if constexpr (sizeof(COUT) == 4)
          C[(size_t)(row0 + r) * 256 + col] = o;
        else
          C[(size_t)(row0 + r) * 256 + col] = f2b(o);
      }
    }
  }
}

// ---------------------------------------------------------------------------
// Fused attention, one block per (head, graph): full 128x128 S, 512 threads.
// S held in LDS as int32 fixed point (s * 2^24); bias accumulation uses
// integer atomicAdd -> native ds_add_u32 (float LDS atomicAdd expands to a
// CAS retry loop -- the measured serializer).  Zero pad slots skipped.
// S columns phi-swizzled (col ^ ((col&0x60)>>2)), softmax reads 2-way.
// LDS 67.6 KB -> 2 blocks/CU.
// ---------------------------------------------------------------------------
__global__ __launch_bounds__(512) void attn_kernel(
    const u16* __restrict__ Q, const u16* __restrict__ K,
    const u16* __restrict__ V, const u32* __restrict__ epos,
    const u16* __restrict__ etot16, u16* __restrict__ O) {
  constexpr int LV = 144, LP = 136, LS = 132;
  __shared__ __align__(16) char smem[67584];
  int*   Si  = (int*)smem;                      // 128*132*4 = 67584 B (S fixp)
  u32*   Su  = (u32*)smem;
  u16*   Pb  = (u16*)smem;                      // 128*136*2 = 34816 B (alias)
  u16*   Vt  = (u16*)(smem + 34816);            // 32*144*2 =  9216 B (alias)
  float* inv = (float*)(smem + 44032);          //   512 B (alias)

  const int tid = threadIdx.x;
  const int h = blockIdx.x, b = blockIdx.y;
  const int wid = tid >> 6, lane = tid & 63;
  const int quad = lane >> 4, l16 = lane & 15;

  // Prefetch this block's edge slice into registers (2304 slots, 512 thr)
  u32 pd[5]; u16 tb[5];
  {
    const u32* ep = epos + (size_t)b * ESTRIDE + tid;
    const u16* ets = etot16 + (size_t)h * (256 * ESTRIDE) + (size_t)b * ESTRIDE + tid;
#pragma unroll
    for (int i = 0; i < 4; ++i) pd[i] = ep[i * 512];
#pragma unroll
    for (int i = 0; i < 4; ++i) tb[i] = ets[i * 512];
    if (tid < 256) { pd[4] = ep[2048]; tb[4] = ets[2048]; }
  }

  // Load V tile into registers (scattered to LDS after softmax)
  const int vr = tid >> 2, vs = (tid & 3) * 8;
  short8 vreg = *(const short8*)(V + (size_t)(b * 128 + vr) * 256 + h * 32 + vs);

  // S = Q @ K^T (scale pre-folded into Q), stored fixed-point.
  {
    short8 aq = *(const short8*)(
        Q + (size_t)(b * 128 + wid * 16 + l16) * 256 + h * 32 + quad * 8);
#pragma unroll
    for (int j = 0; j < 8; ++j) {
      short8 bk = *(const short8*)(
          K + (size_t)(b * 128 + j * 16 + l16) * 256 + h * 32 + quad * 8);
      f32x4 z = {0.f, 0.f, 0.f, 0.f};
      f32x4 sv = MFMA16(aq, bk, z);
      const int cswz = (j >> 1) << 3;  // phi on col block j*16..j*16+15
#pragma unroll
      for (int r = 0; r < 4; ++r)
        Si[(wid * 16 + quad * 4 + r) * LS + ((j * 16 + l16) ^ cswz)] =
            __float2int_rn(sv[r] * FIXSCALE);
    }
  }
  __syncthreads();

  // Edge bias via native integer LDS atomics (phi-swizzled target column)
#pragma unroll
  for (int i = 0; i < 5; ++i) {
    if ((i < 4 || tid < 256) && ((pd[i] | (u32)tb[i]) != 0)) {
      int sl = pd[i] & 0xffff, dl = pd[i] >> 16;
      u32 ti = (u32)__float2int_rn(h2f_bits(tb[i]) * FIXSCALE);
      int dls = dl ^ ((dl & 0x60) >> 2);
      int sls = sl ^ ((sl & 0x60) >> 2);
      atomicAdd(&Su[sl * LS + dls], ti);
      if (sl != dl) atomicAdd(&Su[dl * LS + sls], ti);
    }
  }
  __syncthreads();

  // Softmax: 4 threads/row, phi-swizzled int4 reads return true col order
  {
    int row = tid >> 2, t4 = tid & 3, c0 = t4 * 32;
    const int* srow = &Si[row * LS];
    float sv[32];
#pragma unroll
    for (int k = 0; k < 8; ++k) {
      int4 v = *(const int4*)(srow + ((c0 + k * 4) ^ (t4 << 3)));
      sv[k * 4 + 0] = (float)v.x * FIXINV;
      sv[k * 4 + 1] = (float)v.y * FIXINV;
      sv[k * 4 + 2] = (float)v.z * FIXINV;
      sv[k * 4 + 3] = (float)v.w * FIXINV;
    }
    float m = -1e30f;
#pragma unroll
    for (int c = 0; c < 32; ++c) m = fmaxf(m, sv[c]);
    m = fmaxf(m, __shfl_xor(m, 1, 64));
    m = fmaxf(m, __shfl_xor(m, 2, 64));
    float sum = 0.f;
    short8 prow[4];
#pragma unroll
    for (int c = 0; c < 32; ++c) {
      float p = __expf(sv[c] - m);
      sum += p;
      prow[c >> 3][c & 7] = (short)f2b(p);
    }
    sum += __shfl_xor(sum, 1, 64);
    sum += __shfl_xor(sum, 2, 64);
    __syncthreads();  // all S reads done; Pb/Vt/inv may overwrite S region
#pragma unroll
    for (int k = 0; k < 4; ++k)
      *(short8*)&Pb[row * LP + c0 + k * 8] = prow[k];
#pragma unroll
    for (int j = 0; j < 8; ++j)
      Vt[(vs + j) * LV + vr] = (u16)vreg[j];
    if (t4 == 0) inv[row] = 1.f / sum;
  }
  __syncthreads();

  // O = (P @ V) * inv ; wave wid owns output rows wid*16..+15
  f32x4 oacc[2] = {};
#pragma unroll
  for (int ks = 0; ks < 4; ++ks) {
    short8 ap = *(short8*)&Pb[(wid * 16 + l16) * LP + ks * 32 + quad * 8];
#pragma unroll
    for (int j = 0; j < 2; ++j) {
      short8 bv = *(short8*)&Vt[(j * 16 + l16) * LV + ks * 32 + quad * 8];
      oacc[j] = MFMA16(ap, bv, oacc[j]);
    }
  }
#pragma unroll
  for (int j = 0; j < 2; ++j)
#pragma unroll
    for (int r = 0; r < 4; ++r) {
      int qr = wid * 16 + quad * 4 + r;
      float iv = inv[qr];
      O[(size_t)(b * 128 + qr) * 256 + h * 32 + j * 16 + l16] =
          f2b(oacc[j][r] * iv);
    }
}

// ---------------------------------------------------------------------------

extern "C" void kernel_launch(void* const* d_in, const int* in_sizes, int n_in,
                              void* d_out, int out_size, void* d_ws, size_t ws_size,
                              hipStream_t stream) {
  const float* x    = (const float*)d_in[0];
  const float* ea   = (const float*)d_in[1];
  const float* Wq   = (const float*)d_in[2];
  const float* bq   = (const float*)d_in[3];
  const float* Wk   = (const float*)d_in[4];
  const float* bk   = (const float*)d_in[5];
  const float* Wv   = (const float*)d_in[6];
  const float* bv   = (const float*)d_in[7];
  const float* Wo   = (const float*)d_in[8];
  const float* bo   = (const float*)d_in[9];
  const float* gate = (const float*)d_in[10];
  const float* We   = (const float*)d_in[11];
  const float* be   = (const float*)d_in[12];
  const int*   ei   = (const int*)d_in[13];
  const int*   egt  = (const int*)d_in[14];
  const int    E    = in_sizes[14];

  const size_t matBytes = (size_t)32768 * 256 * 2;   // 16.78 MB per bf16 matrix
  const size_t slots = (size_t)256 * ESTRIDE;        // 589824

  char* ws = (char*)d_ws;
  u16* Qm = (u16*)ws;
  u16* Km = (u16*)(ws + matBytes);
  u16* Vm = (u16*)(ws + 2 * matBytes);
  u16* Om = (u16*)(ws + 3 * matBytes);
  u16* xb = Om;  // xb aliases Om: xb dead before attn writes Om
  u16*   etA  = (u16*)(ws + 4 * matBytes);                 // slots*8 fp16 AoS
  u16*   etS  = etA + slots * 8;                           // slots*8 fp16 SoA
  u32*   epos = (u32*)(etS + slots * 8);                   // slots u32
  u32*   gfill = (u32*)((char*)epos + slots * 4);          // 256 ctrs, 64B apart
  u16*   Wtq = (u16*)((char*)gfill + 4096 * 4);            // 4 x 64K bf16
  u16*   Wtk = Wtq + 65536;
  u16*   Wtv = Wtk + 65536;
  u16*   Wto = Wtv + 65536;

  hipMemsetAsync(gfill, 0, 4096 * sizeof(u32), stream);

  edge_build_kernel<<<dim3((E + 2047) / 2048), dim3(256), 0, stream>>>(
      ei, ea, egt, gate, We, be, gfill, etA, epos, E);
  etrans_pad_kernel<<<dim3(ESTRIDE / 256, 256), dim3(256), 0, stream>>>(
      etA, gfill, etS, epos);

  cvt_wtrans_kernel<<<dim3(4224), dim3(256), 0, stream>>>(
      x, xb, Wq, Wk, Wv, Wo, Wtq, Wtk, Wtv, Wto);

  const float qscale = 0.17677669529663687f;
  gemm_tiled_kernel<3, u16><<<dim3(256, 6), dim3(256), 0, stream>>>(
      xb, Wtq, Wtk, Wtv, bq, bk, bv, qscale, 1.f, 1.f, Qm, Km, Vm);

  attn_kernel<<<dim3(8, 256), dim3(512), 0, stream>>>(
      Qm, Km, Vm, epos, etS, Om);

  gemm_tiled_kernel<1, float><<<dim3(256, 2), dim3(256), 0, stream>>>(
      Om, Wto, nullptr, nullptr, bo, nullptr, nullptr, 1.f, 1.f, 1.f,
      (float*)d_out, nullptr, nullptr);
}